// Round 8
// baseline (314.908 us; speedup 1.0000x reference)
//
#include <hip/hip_runtime.h>
#include <hip/hip_bf16.h>
#include <cstdint>

#define TOKENS 8192
#define IN_F   4096
#define OUT_F  4096

#define BM 256
#define BN 256
#define BK 64
#define NT (IN_F / BK)   // 64 K-tiles
#define THREADS 512

typedef __attribute__((ext_vector_type(8))) short bf16x8;
typedef __attribute__((ext_vector_type(4))) float f32x4;

#define GLOBAL_AS __attribute__((address_space(1)))
#define LDS_AS    __attribute__((address_space(3)))

// NO memory clobbers anywhere (r8 fix): an INLINEASM with a "memory" clobber
// is treated as mayLoad/mayStore by the waitcnt pass -> conservative full
// drains at every barrier = the m218 "drain0" regime. m201's verified pattern
// uses bare builtins + clobber-free asm waits.
#define BARRIER() __builtin_amdgcn_s_barrier()
#define WAIT_LGKM0() do { asm volatile("s_waitcnt lgkmcnt(0)"); \
                          __builtin_amdgcn_sched_barrier(0); } while (0)
#define VMCNT(n)  do { asm volatile("s_waitcnt vmcnt(" #n ")"); \
                       __builtin_amdgcn_sched_barrier(0); } while (0)

__device__ __forceinline__ unsigned short f2bf(float f) {
  union { float f; unsigned int u; } v;
  v.f = f;
  unsigned int r = 0x7FFFu + ((v.u >> 16) & 1u);
  return (unsigned short)((v.u + r) >> 16);
}

__device__ __forceinline__ float softplus_f(float x) {
  return log1pf(expf(x));
}

// ---------------- fused prep kernel ----------------

#define NW4 ((long long)OUT_F * IN_F / 4)
#define NX4 ((long long)TOKENS * IN_F / 4)
#define NB4 (OUT_F / 4)

__global__ void prep_kernel(const float* __restrict__ x,
                            const float* __restrict__ wmu,
                            const float* __restrict__ wrho,
                            const float* __restrict__ weps,
                            const float* __restrict__ bmu,
                            const float* __restrict__ brho,
                            const float* __restrict__ beps,
                            unsigned short* __restrict__ xb,
                            unsigned short* __restrict__ wb,
                            float* __restrict__ bias) {
  long long i = (long long)blockIdx.x * blockDim.x + threadIdx.x;
  long long stride = (long long)gridDim.x * blockDim.x;
  const long long total = NW4 + NX4 + NB4;
  for (; i < total; i += stride) {
    if (i < NW4) {
      float4 m = reinterpret_cast<const float4*>(wmu)[i];
      float4 r = reinterpret_cast<const float4*>(wrho)[i];
      float4 e = reinterpret_cast<const float4*>(weps)[i];
      ushort4 o;
      o.x = f2bf(fmaf(softplus_f(r.x), e.x, m.x));
      o.y = f2bf(fmaf(softplus_f(r.y), e.y, m.y));
      o.z = f2bf(fmaf(softplus_f(r.z), e.z, m.z));
      o.w = f2bf(fmaf(softplus_f(r.w), e.w, m.w));
      reinterpret_cast<ushort4*>(wb)[i] = o;
    } else if (i < NW4 + NX4) {
      long long j = i - NW4;
      float4 m = reinterpret_cast<const float4*>(x)[j];
      ushort4 o;
      o.x = f2bf(m.x); o.y = f2bf(m.y); o.z = f2bf(m.z); o.w = f2bf(m.w);
      reinterpret_cast<ushort4*>(xb)[j] = o;
    } else {
      long long j = i - NW4 - NX4;
      float4 m = reinterpret_cast<const float4*>(bmu)[j];
      float4 r = reinterpret_cast<const float4*>(brho)[j];
      float4 e = reinterpret_cast<const float4*>(beps)[j];
      float4 o;
      o.x = fmaf(softplus_f(r.x), e.x, m.x);
      o.y = fmaf(softplus_f(r.y), e.y, m.y);
      o.z = fmaf(softplus_f(r.z), e.z, m.z);
      o.w = fmaf(softplus_f(r.w), e.w, m.w);
      reinterpret_cast<float4*>(bias)[j] = o;
    }
  }
}

// ---------------- GEMM: 256x256, m201-faithful 4-phase/tile schedule ----------------
// LDS 160 KiB: A ring 3 x 32 KiB + B ring 2 x 32 KiB. 8 waves (2M x 4N),
// per-wave out 128x64. Phase = {ds_reads; stage; [lgkm(8)]; barrier; lgkm(0)+
// sched_barrier; setprio(1); 16 MFMA; setprio(0); [vmcnt @ph3]; barrier}.
// Reads consumed same-phase; overlap comes from wave-skew at the leading
// barrier (early waves' reads run while laggards MFMA).
// vmcnt ledger (2 loads per stage-call, 4 calls/tile): entering tile t with
// 6 outstanding = (t+1).{A1,B0,B1}; +8 during t; VMCNT(6) at ph3 waits the
// oldest 8 -> tile t+1 fully landed (+barrier = global publish), leaves
// (t+2).{A1,B0,B1} in flight. Prologue: t0+t1 (16 loads), VMCNT(8).
// Slot liveness: A slot (t+2)%3 last read ph3(t-1) [drained by its lgkm(0)];
// B slot t&1 last read ph0(t) [drained by ph0's lgkm(0)] -> writes at
// ph0..ph3 of t are safe.
// LDS swizzle: chunk ^= (row & 7) via pre-swizzled global source (linear
// global_load_lds dest) + matching XOR on ds_read (rule 21 involution).

__global__ __launch_bounds__(THREADS, 2) void gemm_bt_kernel(
    const unsigned short* __restrict__ A,   // [TOKENS][IN_F] bf16
    const unsigned short* __restrict__ B,   // [OUT_F][IN_F] bf16
    const float* __restrict__ bias,         // [OUT_F]
    float* __restrict__ C)                  // [TOKENS][OUT_F]
{
  __shared__ unsigned short lds[5 * 16384]; // 160 KiB

  const int tid  = threadIdx.x;
  const int lane = tid & 63;
  const int wave = tid >> 6;   // 0..7
  const int wm   = wave >> 2;  // 0..1
  const int wn   = wave & 3;   // 0..3

  // XCD-aware bijective block swizzle (512 = 8 XCD chunks x 64)
  const int bid = blockIdx.x;
  const int wg  = (bid & 7) * 64 + (bid >> 3);
  const int ch  = wg >> 6;
  const int idx = wg & 63;
  const int bm  = (ch >> 1) * 8 + (idx >> 3);  // 0..31
  const int bn  = (ch & 1) * 8 + (idx & 7);    // 0..15

  const int lane15 = lane & 15;
  const int cgrp   = lane >> 4;                // 0..3
  const int rdoff0 = lane15 * 64 + ((cgrp ^ (lane & 7)) * 8);
  const int rdoff1 = lane15 * 64 + (((4 + cgrp) ^ (lane & 7)) * 8);

  // staging: per-lane pre-swizzled global source
  const int srow = lane >> 3;                  // 0..7
  const int scol = ((lane & 7) ^ srow) * 8;    // swizzled 16B chunk -> elems
  const unsigned short* Asrc = A + (size_t)(bm * BM + wave * 16 + srow) * IN_F + scol;
  const unsigned short* Bsrc = B + (size_t)(bn * BN + wave * 16 + srow) * IN_F + scol;

  f32x4 acc[8][4] = {};

  auto stA = [&](int slot, int half, int t) {
    unsigned short* dst = &lds[slot * 16384 + half * 8192 + wave * 1024];
    const unsigned short* g = Asrc + (size_t)(half * 128) * IN_F + t * BK;
    __builtin_amdgcn_global_load_lds((const GLOBAL_AS void*)g,
                                     (LDS_AS void*)dst, 16, 0, 0);
    __builtin_amdgcn_global_load_lds((const GLOBAL_AS void*)(g + (size_t)8 * IN_F),
                                     (LDS_AS void*)(dst + 512), 16, 0, 0);
  };
  auto stB = [&](int slot, int half, int t) {
    unsigned short* dst = &lds[49152 + slot * 16384 + half * 8192 + wave * 1024];
    const unsigned short* g = Bsrc + (size_t)(half * 128) * IN_F + t * BK;
    __builtin_amdgcn_global_load_lds((const GLOBAL_AS void*)g,
                                     (LDS_AS void*)dst, 16, 0, 0);
    __builtin_amdgcn_global_load_lds((const GLOBAL_AS void*)(g + (size_t)8 * IN_F),
                                     (LDS_AS void*)(dst + 512), 16, 0, 0);
  };

  auto rdA = [&](const unsigned short* Ar, int q, bf16x8 (&av)[2][2]) {
#pragma unroll
    for (int f = 0; f < 2; ++f) {
      const unsigned short* p = Ar + (wm * 128 + q * 32 + f * 16) * 64;
      av[f][0] = *reinterpret_cast<const bf16x8*>(p + rdoff0);
      av[f][1] = *reinterpret_cast<const bf16x8*>(p + rdoff1);
    }
  };
  auto rdB = [&](const unsigned short* Br, bf16x8 (&bv)[4][2]) {
#pragma unroll
    for (int n = 0; n < 4; ++n) {
      const unsigned short* p = Br + (wn * 64 + n * 16) * 64;
      bv[n][0] = *reinterpret_cast<const bf16x8*>(p + rdoff0);
      bv[n][1] = *reinterpret_cast<const bf16x8*>(p + rdoff1);
    }
  };
  auto mfma16 = [&](bf16x8 (&av)[2][2], bf16x8 (&bv)[4][2], f32x4* r0, f32x4* r1) {
    __builtin_amdgcn_s_setprio(1);
#pragma unroll
    for (int kk = 0; kk < 2; ++kk) {
#pragma unroll
      for (int n = 0; n < 4; ++n) {
        r0[n] = __builtin_amdgcn_mfma_f32_16x16x32_bf16(av[0][kk], bv[n][kk], r0[n], 0, 0, 0);
        r1[n] = __builtin_amdgcn_mfma_f32_16x16x32_bf16(av[1][kk], bv[n][kk], r1[n], 0, 0, 0);
      }
    }
    __builtin_amdgcn_s_setprio(0);
  };

  // prologue: stage t0 fully, then t1 fully; wait t0 (8 newest stay in flight)
  stA(0, 0, 0); stA(0, 1, 0); stB(0, 0, 0); stB(0, 1, 0);
  stA(1, 0, 1); stA(1, 1, 1); stB(1, 0, 1); stB(1, 1, 1);
  VMCNT(8);
  BARRIER();

  int aslot = 0, bslot = 0;
  for (int t = 0; t < NT; ++t) {
    const unsigned short* As = &lds[aslot * 16384];
    const unsigned short* Bs = &lds[49152 + bslot * 16384];
    int a2 = aslot + 2; if (a2 >= 3) a2 -= 3;   // A slot of tile t+2
    const bool pf = (t + 2 < NT);
    bf16x8 av[2][2], bv[4][2];

    // ---- ph0: read B (8) + A q0 (4); stage (t+2).A0 ----
    rdB(Bs, bv); rdA(As, 0, av);
    if (pf) stA(a2, 0, t + 2);
    asm volatile("s_waitcnt lgkmcnt(8)");
    BARRIER();
    WAIT_LGKM0();
    mfma16(av, bv, acc[0], acc[1]);
    BARRIER();

    // ---- ph1: read A q1; stage (t+2).A1 ----
    rdA(As, 1, av);
    if (pf) stA(a2, 1, t + 2);
    BARRIER();
    WAIT_LGKM0();
    mfma16(av, bv, acc[2], acc[3]);
    BARRIER();

    // ---- ph2: read A q2; stage (t+2).B0 ----
    rdA(As, 2, av);
    if (pf) stB(bslot, 0, t + 2);
    BARRIER();
    WAIT_LGKM0();
    mfma16(av, bv, acc[4], acc[5]);
    BARRIER();

    // ---- ph3: read A q3; stage (t+2).B1; counted boundary wait ----
    rdA(As, 3, av);
    if (pf) stB(bslot, 1, t + 2);
    BARRIER();
    WAIT_LGKM0();
    mfma16(av, bv, acc[6], acc[7]);
    if (pf)               { VMCNT(6); }   // t+1 landed; (t+2).{A1,B0,B1} in flight
    else if (t + 1 < NT)  { VMCNT(0); }   // drain last prefetch
    BARRIER();

    aslot = (aslot == 2) ? 0 : aslot + 1;
    bslot ^= 1;
  }

  // epilogue: C/D layout col=lane&15, row=(lane>>4)*4+reg
  const int colg0 = bn * BN + wn * 64 + lane15;
  const int rowg0 = bm * BM + wm * 128 + (lane >> 4) * 4;
#pragma unroll
  for (int ni = 0; ni < 4; ++ni) {
    const int colg = colg0 + ni * 16;
    const float bvs = bias[colg];
#pragma unroll
    for (int mi = 0; mi < 8; ++mi) {
      const int rowg = rowg0 + mi * 16;
#pragma unroll
      for (int r = 0; r < 4; ++r)
        C[(size_t)(rowg + r) * OUT_F + colg] = acc[mi][ni][r] + bvs;
    }
  }
}

// ---------------- fallback (only if ws too small) ----------------

__global__ void fallback_kernel(const float* __restrict__ x,
                                const float* __restrict__ wmu,
                                const float* __restrict__ wrho,
                                const float* __restrict__ weps,
                                const float* __restrict__ bmu,
                                const float* __restrict__ brho,
                                const float* __restrict__ beps,
                                float* __restrict__ out) {
  int o = blockIdx.x * blockDim.x + threadIdx.x;
  int t = blockIdx.y;
  float s = 0.f;
  const float* xr = x + (size_t)t * IN_F;
  const float* wm = wmu + (size_t)o * IN_F;
  const float* wr = wrho + (size_t)o * IN_F;
  const float* we = weps + (size_t)o * IN_F;
  for (int k = 0; k < IN_F; ++k)
    s += xr[k] * fmaf(softplus_f(wr[k]), we[k], wm[k]);
  out[(size_t)t * OUT_F + o] = s + fmaf(softplus_f(brho[o]), beps[o], bmu[o]);
}

// ---------------- launch ----------------

extern "C" void kernel_launch(void* const* d_in, const int* in_sizes, int n_in,
                              void* d_out, int out_size, void* d_ws, size_t ws_size,
                              hipStream_t stream) {
  const float* x    = (const float*)d_in[0];
  const float* wmu  = (const float*)d_in[1];
  const float* wrho = (const float*)d_in[2];
  const float* bmu  = (const float*)d_in[3];
  const float* brho = (const float*)d_in[4];
  const float* weps = (const float*)d_in[5];
  const float* beps = (const float*)d_in[6];
  float* out = (float*)d_out;

  const size_t xb_off   = 0;
  const size_t wb_off   = (size_t)TOKENS * IN_F * 2;            // 64 MB
  const size_t bias_off = wb_off + (size_t)OUT_F * IN_F * 2;    // +32 MB
  const size_t needed   = bias_off + (size_t)OUT_F * 4;

  if (ws_size < needed) {
    dim3 g(OUT_F / 256, TOKENS);
    hipLaunchKernelGGL(fallback_kernel, g, dim3(256), 0, stream,
                       x, wmu, wrho, weps, bmu, brho, beps, out);
    return;
  }

  unsigned short* xb = (unsigned short*)((char*)d_ws + xb_off);
  unsigned short* wb = (unsigned short*)((char*)d_ws + wb_off);
  float* bias = (float*)((char*)d_ws + bias_off);

  hipLaunchKernelGGL(prep_kernel, dim3(2048), dim3(256), 0, stream,
                     x, wmu, wrho, weps, bmu, brho, beps, xb, wb, bias);

  hipLaunchKernelGGL(gemm_bt_kernel,
                     dim3((TOKENS / BM) * (OUT_F / BN)), dim3(THREADS), 0, stream,
                     xb, wb, bias, out);
}

// Round 9
// 313.420 us; speedup vs baseline: 1.0047x; 1.0047x over previous
//
#include <hip/hip_runtime.h>
#include <hip/hip_bf16.h>
#include <cstdint>

#define TOKENS 8192
#define IN_F   4096
#define OUT_F  4096

#define BM 256
#define BN 256
#define BK 64
#define NT (IN_F / BK)   // 64 K-tiles
#define THREADS 512

typedef __attribute__((ext_vector_type(8))) short bf16x8;
typedef __attribute__((ext_vector_type(4))) float f32x4;

#define GLOBAL_AS __attribute__((address_space(1)))
#define LDS_AS    __attribute__((address_space(3)))

// clobber-free sync (r8); counted LGKM waits for the free-flow pipeline (r9).
// sched_barrier(0) after each wait: rule 18 (stops MFMA hoisting past the wait).
#define BARRIER() __builtin_amdgcn_s_barrier()
#define LGKM(n)   do { asm volatile("s_waitcnt lgkmcnt(" #n ")"); \
                       __builtin_amdgcn_sched_barrier(0); } while (0)
#define VMCNT(n)  do { asm volatile("s_waitcnt vmcnt(" #n ")"); \
                       __builtin_amdgcn_sched_barrier(0); } while (0)

__device__ __forceinline__ unsigned short f2bf(float f) {
  union { float f; unsigned int u; } v;
  v.f = f;
  unsigned int r = 0x7FFFu + ((v.u >> 16) & 1u);
  return (unsigned short)((v.u + r) >> 16);
}

__device__ __forceinline__ float softplus_f(float x) {
  return log1pf(expf(x));
}

// ---------------- fused prep kernel ----------------

#define NW4 ((long long)OUT_F * IN_F / 4)
#define NX4 ((long long)TOKENS * IN_F / 4)
#define NB4 (OUT_F / 4)

__global__ void prep_kernel(const float* __restrict__ x,
                            const float* __restrict__ wmu,
                            const float* __restrict__ wrho,
                            const float* __restrict__ weps,
                            const float* __restrict__ bmu,
                            const float* __restrict__ brho,
                            const float* __restrict__ beps,
                            unsigned short* __restrict__ xb,
                            unsigned short* __restrict__ wb,
                            float* __restrict__ bias) {
  long long i = (long long)blockIdx.x * blockDim.x + threadIdx.x;
  long long stride = (long long)gridDim.x * blockDim.x;
  const long long total = NW4 + NX4 + NB4;
  for (; i < total; i += stride) {
    if (i < NW4) {
      float4 m = reinterpret_cast<const float4*>(wmu)[i];
      float4 r = reinterpret_cast<const float4*>(wrho)[i];
      float4 e = reinterpret_cast<const float4*>(weps)[i];
      ushort4 o;
      o.x = f2bf(fmaf(softplus_f(r.x), e.x, m.x));
      o.y = f2bf(fmaf(softplus_f(r.y), e.y, m.y));
      o.z = f2bf(fmaf(softplus_f(r.z), e.z, m.z));
      o.w = f2bf(fmaf(softplus_f(r.w), e.w, m.w));
      reinterpret_cast<ushort4*>(wb)[i] = o;
    } else if (i < NW4 + NX4) {
      long long j = i - NW4;
      float4 m = reinterpret_cast<const float4*>(x)[j];
      ushort4 o;
      o.x = f2bf(m.x); o.y = f2bf(m.y); o.z = f2bf(m.z); o.w = f2bf(m.w);
      reinterpret_cast<ushort4*>(xb)[j] = o;
    } else {
      long long j = i - NW4 - NX4;
      float4 m = reinterpret_cast<const float4*>(bmu)[j];
      float4 r = reinterpret_cast<const float4*>(brho)[j];
      float4 e = reinterpret_cast<const float4*>(beps)[j];
      float4 o;
      o.x = fmaf(softplus_f(r.x), e.x, m.x);
      o.y = fmaf(softplus_f(r.y), e.y, m.y);
      o.z = fmaf(softplus_f(r.z), e.z, m.z);
      o.w = fmaf(softplus_f(r.w), e.w, m.w);
      reinterpret_cast<float4*>(bias)[j] = o;
    }
  }
}

// ---------------- GEMM: 256x256, FREE-FLOW tile, 2 barriers/tile ----------------
// LDS 160 KiB: A ring 3 x 32 KiB + B ring 2 x 32 KiB. 8 waves (2M x 4N),
// per-wave out 128x64. r9: intra-tile sync is per-wave counted lgkmcnt only
// (DS ops retire in order), so each wave software-pipelines reads one quadrant
// ahead of its MFMA and waves drift apart — LDS pipe (per-CU, 2300 cyc/tile)
// overlaps MFMA pipes (per-SIMD, 2480 cyc/tile) via wave asymmetry instead of
// barrier-locked bursts.
//   bar1 (after q0-MFMA): every wave's LGKM(4) has drained its B reads before
//     it arrives => stB(bslot, t+2) after bar1 cannot race tile-t B reads.
//   bar2 (after VMCNT(6)): publishes tile t+1 staging; also orders A-ring:
//     slot (t+2)%3 was last read at t-1, and each wave's LGKM(0) before its
//     q3-MFMA drained those reads before bar2(t-1) < stA issue at t.
// vmcnt ledger (issue order stA0,stA1,stB0,stB1; 2 loads/call): steady 6 in
// flight entering a tile; +8 during; VMCNT(6) drains prior 6 + new A0 pair
// => tile t+1 fully landed, (t+2).{A1,B0,B1} stay in flight.
// LDS swizzle: chunk ^= (row & 7) via pre-swizzled global source (linear
// global_load_lds dest) + matching XOR on ds_read (rule 21 involution).

__global__ __launch_bounds__(THREADS, 2) void gemm_bt_kernel(
    const unsigned short* __restrict__ A,   // [TOKENS][IN_F] bf16
    const unsigned short* __restrict__ B,   // [OUT_F][IN_F] bf16
    const float* __restrict__ bias,         // [OUT_F]
    float* __restrict__ C)                  // [TOKENS][OUT_F]
{
  __shared__ unsigned short lds[5 * 16384]; // 160 KiB

  const int tid  = threadIdx.x;
  const int lane = tid & 63;
  const int wave = tid >> 6;   // 0..7
  const int wm   = wave >> 2;  // 0..1
  const int wn   = wave & 3;   // 0..3

  // XCD-aware bijective block swizzle (512 = 8 XCD chunks x 64)
  const int bid = blockIdx.x;
  const int wg  = (bid & 7) * 64 + (bid >> 3);
  const int ch  = wg >> 6;
  const int idx = wg & 63;
  const int bm  = (ch >> 1) * 8 + (idx >> 3);  // 0..31
  const int bn  = (ch & 1) * 8 + (idx & 7);    // 0..15

  const int lane15 = lane & 15;
  const int cgrp   = lane >> 4;                // 0..3
  const int rdoff0 = lane15 * 64 + ((cgrp ^ (lane & 7)) * 8);
  const int rdoff1 = lane15 * 64 + (((4 + cgrp) ^ (lane & 7)) * 8);

  // staging: per-lane pre-swizzled global source
  const int srow = lane >> 3;                  // 0..7
  const int scol = ((lane & 7) ^ srow) * 8;    // swizzled 16B chunk -> elems
  const unsigned short* Asrc = A + (size_t)(bm * BM + wave * 16 + srow) * IN_F + scol;
  const unsigned short* Bsrc = B + (size_t)(bn * BN + wave * 16 + srow) * IN_F + scol;

  f32x4 acc[8][4] = {};

  auto stA = [&](int slot, int half, int t) {
    unsigned short* dst = &lds[slot * 16384 + half * 8192 + wave * 1024];
    const unsigned short* g = Asrc + (size_t)(half * 128) * IN_F + t * BK;
    __builtin_amdgcn_global_load_lds((const GLOBAL_AS void*)g,
                                     (LDS_AS void*)dst, 16, 0, 0);
    __builtin_amdgcn_global_load_lds((const GLOBAL_AS void*)(g + (size_t)8 * IN_F),
                                     (LDS_AS void*)(dst + 512), 16, 0, 0);
  };
  auto stB = [&](int slot, int half, int t) {
    unsigned short* dst = &lds[49152 + slot * 16384 + half * 8192 + wave * 1024];
    const unsigned short* g = Bsrc + (size_t)(half * 128) * IN_F + t * BK;
    __builtin_amdgcn_global_load_lds((const GLOBAL_AS void*)g,
                                     (LDS_AS void*)dst, 16, 0, 0);
    __builtin_amdgcn_global_load_lds((const GLOBAL_AS void*)(g + (size_t)8 * IN_F),
                                     (LDS_AS void*)(dst + 512), 16, 0, 0);
  };

  auto rdA = [&](const unsigned short* Ar, int q, bf16x8 (&av)[2][2]) {
#pragma unroll
    for (int f = 0; f < 2; ++f) {
      const unsigned short* p = Ar + (wm * 128 + q * 32 + f * 16) * 64;
      av[f][0] = *reinterpret_cast<const bf16x8*>(p + rdoff0);
      av[f][1] = *reinterpret_cast<const bf16x8*>(p + rdoff1);
    }
  };
  auto rdB = [&](const unsigned short* Br, bf16x8 (&bv)[4][2]) {
#pragma unroll
    for (int n = 0; n < 4; ++n) {
      const unsigned short* p = Br + (wn * 64 + n * 16) * 64;
      bv[n][0] = *reinterpret_cast<const bf16x8*>(p + rdoff0);
      bv[n][1] = *reinterpret_cast<const bf16x8*>(p + rdoff1);
    }
  };
  auto mfma16 = [&](bf16x8 (&av)[2][2], bf16x8 (&bv)[4][2], f32x4* r0, f32x4* r1) {
    __builtin_amdgcn_s_setprio(1);
#pragma unroll
    for (int kk = 0; kk < 2; ++kk) {
#pragma unroll
      for (int n = 0; n < 4; ++n) {
        r0[n] = __builtin_amdgcn_mfma_f32_16x16x32_bf16(av[0][kk], bv[n][kk], r0[n], 0, 0, 0);
        r1[n] = __builtin_amdgcn_mfma_f32_16x16x32_bf16(av[1][kk], bv[n][kk], r1[n], 0, 0, 0);
      }
    }
    __builtin_amdgcn_s_setprio(0);
  };

  // prologue: stage t0 fully, then t1 fully; wait t0 (8 newest stay in flight)
  stA(0, 0, 0); stA(0, 1, 0); stB(0, 0, 0); stB(0, 1, 0);
  stA(1, 0, 1); stA(1, 1, 1); stB(1, 0, 1); stB(1, 1, 1);
  VMCNT(8);
  BARRIER();

  int aslot = 0, bslot = 0;
  for (int t = 0; t < NT; ++t) {
    const unsigned short* As = &lds[aslot * 16384];
    const unsigned short* Bs = &lds[49152 + bslot * 16384];
    int a2 = aslot + 2; if (a2 >= 3) a2 -= 3;   // A slot of tile t+2
    const bool pf = (t + 2 < NT);
    bf16x8 avX[2][2], avY[2][2], bv[4][2];

    // ---- free-flow body: reads run one quadrant ahead of MFMA ----
    rdB(Bs, bv);                                 // 8 ds
    rdA(As, 0, avX);                             // +4 = 12
    if (pf) { stA(a2, 0, t + 2); stA(a2, 1, t + 2); }   // vm +4
    rdA(As, 1, avY);                             // +4 = 16 outstanding
    LGKM(4);                                     // B + q0 ready; q1 in flight
    mfma16(avX, bv, acc[0], acc[1]);             // q0
    BARRIER();   // bar1: all waves' B reads drained (their LGKM(4)) before stB

    if (pf) stB(bslot, 0, t + 2);                // vm +2
    rdA(As, 2, avX);                             // q1 + q2 in flight
    LGKM(4);                                     // q1 ready
    mfma16(avY, bv, acc[2], acc[3]);             // q1
    if (pf) stB(bslot, 1, t + 2);                // vm +2
    rdA(As, 3, avY);                             // q2 + q3 in flight
    LGKM(4);                                     // q2 ready
    mfma16(avX, bv, acc[4], acc[5]);             // q2
    LGKM(0);                                     // q3 ready
    mfma16(avY, bv, acc[6], acc[7]);             // q3

    // boundary: publish tile t+1 (counted; never drain in steady state)
    if (pf)              { VMCNT(6); }
    else if (t + 1 < NT) { VMCNT(0); }
    if (t + 1 < NT) BARRIER();                   // bar2

    aslot = (aslot == 2) ? 0 : aslot + 1;
    bslot ^= 1;
  }

  // epilogue: C/D layout col=lane&15, row=(lane>>4)*4+reg
  const int colg0 = bn * BN + wn * 64 + lane15;
  const int rowg0 = bm * BM + wm * 128 + (lane >> 4) * 4;
#pragma unroll
  for (int ni = 0; ni < 4; ++ni) {
    const int colg = colg0 + ni * 16;
    const float bvs = bias[colg];
#pragma unroll
    for (int mi = 0; mi < 8; ++mi) {
      const int rowg = rowg0 + mi * 16;
#pragma unroll
      for (int r = 0; r < 4; ++r)
        C[(size_t)(rowg + r) * OUT_F + colg] = acc[mi][ni][r] + bvs;
    }
  }
}

// ---------------- fallback (only if ws too small) ----------------

__global__ void fallback_kernel(const float* __restrict__ x,
                                const float* __restrict__ wmu,
                                const float* __restrict__ wrho,
                                const float* __restrict__ weps,
                                const float* __restrict__ bmu,
                                const float* __restrict__ brho,
                                const float* __restrict__ beps,
                                float* __restrict__ out) {
  int o = blockIdx.x * blockDim.x + threadIdx.x;
  int t = blockIdx.y;
  float s = 0.f;
  const float* xr = x + (size_t)t * IN_F;
  const float* wm = wmu + (size_t)o * IN_F;
  const float* wr = wrho + (size_t)o * IN_F;
  const float* we = weps + (size_t)o * IN_F;
  for (int k = 0; k < IN_F; ++k)
    s += xr[k] * fmaf(softplus_f(wr[k]), we[k], wm[k]);
  out[(size_t)t * OUT_F + o] = s + fmaf(softplus_f(brho[o]), beps[o], bmu[o]);
}

// ---------------- launch ----------------

extern "C" void kernel_launch(void* const* d_in, const int* in_sizes, int n_in,
                              void* d_out, int out_size, void* d_ws, size_t ws_size,
                              hipStream_t stream) {
  const float* x    = (const float*)d_in[0];
  const float* wmu  = (const float*)d_in[1];
  const float* wrho = (const float*)d_in[2];
  const float* bmu  = (const float*)d_in[3];
  const float* brho = (const float*)d_in[4];
  const float* weps = (const float*)d_in[5];
  const float* beps = (const float*)d_in[6];
  float* out = (float*)d_out;

  const size_t xb_off   = 0;
  const size_t wb_off   = (size_t)TOKENS * IN_F * 2;            // 64 MB
  const size_t bias_off = wb_off + (size_t)OUT_F * IN_F * 2;    // +32 MB
  const size_t needed   = bias_off + (size_t)OUT_F * 4;

  if (ws_size < needed) {
    dim3 g(OUT_F / 256, TOKENS);
    hipLaunchKernelGGL(fallback_kernel, g, dim3(256), 0, stream,
                       x, wmu, wrho, weps, bmu, brho, beps, out);
    return;
  }

  unsigned short* xb = (unsigned short*)((char*)d_ws + xb_off);
  unsigned short* wb = (unsigned short*)((char*)d_ws + wb_off);
  float* bias = (float*)((char*)d_ws + bias_off);

  hipLaunchKernelGGL(prep_kernel, dim3(2048), dim3(256), 0, stream,
                     x, wmu, wrho, weps, bmu, brho, beps, xb, wb, bias);

  hipLaunchKernelGGL(gemm_bt_kernel,
                     dim3((TOKENS / BM) * (OUT_F / BN)), dim3(THREADS), 0, stream,
                     xb, wb, bias, out);
}

// Round 10
// 312.464 us; speedup vs baseline: 1.0078x; 1.0031x over previous
//
#include <hip/hip_runtime.h>
#include <hip/hip_bf16.h>
#include <cstdint>

#define TOKENS 8192
#define IN_F   4096
#define OUT_F  4096

#define BM 256
#define BN 256
#define BK 64
#define NT (IN_F / BK)   // 64 K-tiles
#define THREADS 256      // 4 waves = 1 wave/SIMD: per-wave self-overlap

typedef __attribute__((ext_vector_type(8))) short bf16x8;
typedef __attribute__((ext_vector_type(4))) float f32x4;

#define GLOBAL_AS __attribute__((address_space(1)))
#define LDS_AS    __attribute__((address_space(3)))

#define BARRIER() __builtin_amdgcn_s_barrier()
#define LGKM(n)   do { asm volatile("s_waitcnt lgkmcnt(" #n ")"); \
                       __builtin_amdgcn_sched_barrier(0); } while (0)
#define VMCNT(n)  do { asm volatile("s_waitcnt vmcnt(" #n ")"); \
                       __builtin_amdgcn_sched_barrier(0); } while (0)

__device__ __forceinline__ unsigned short f2bf(float f) {
  union { float f; unsigned int u; } v;
  v.f = f;
  unsigned int r = 0x7FFFu + ((v.u >> 16) & 1u);
  return (unsigned short)((v.u + r) >> 16);
}

__device__ __forceinline__ float softplus_f(float x) {
  return log1pf(expf(x));
}

// ---------------- fused prep kernel ----------------

#define NW4 ((long long)OUT_F * IN_F / 4)
#define NX4 ((long long)TOKENS * IN_F / 4)
#define NB4 (OUT_F / 4)

__global__ void prep_kernel(const float* __restrict__ x,
                            const float* __restrict__ wmu,
                            const float* __restrict__ wrho,
                            const float* __restrict__ weps,
                            const float* __restrict__ bmu,
                            const float* __restrict__ brho,
                            const float* __restrict__ beps,
                            unsigned short* __restrict__ xb,
                            unsigned short* __restrict__ wb,
                            float* __restrict__ bias) {
  long long i = (long long)blockIdx.x * blockDim.x + threadIdx.x;
  long long stride = (long long)gridDim.x * blockDim.x;
  const long long total = NW4 + NX4 + NB4;
  for (; i < total; i += stride) {
    if (i < NW4) {
      float4 m = reinterpret_cast<const float4*>(wmu)[i];
      float4 r = reinterpret_cast<const float4*>(wrho)[i];
      float4 e = reinterpret_cast<const float4*>(weps)[i];
      ushort4 o;
      o.x = f2bf(fmaf(softplus_f(r.x), e.x, m.x));
      o.y = f2bf(fmaf(softplus_f(r.y), e.y, m.y));
      o.z = f2bf(fmaf(softplus_f(r.z), e.z, m.z));
      o.w = f2bf(fmaf(softplus_f(r.w), e.w, m.w));
      reinterpret_cast<ushort4*>(wb)[i] = o;
    } else if (i < NW4 + NX4) {
      long long j = i - NW4;
      float4 m = reinterpret_cast<const float4*>(x)[j];
      ushort4 o;
      o.x = f2bf(m.x); o.y = f2bf(m.y); o.z = f2bf(m.z); o.w = f2bf(m.w);
      reinterpret_cast<ushort4*>(xb)[j] = o;
    } else {
      long long j = i - NW4 - NX4;
      float4 m = reinterpret_cast<const float4*>(bmu)[j];
      float4 r = reinterpret_cast<const float4*>(brho)[j];
      float4 e = reinterpret_cast<const float4*>(beps)[j];
      float4 o;
      o.x = fmaf(softplus_f(r.x), e.x, m.x);
      o.y = fmaf(softplus_f(r.y), e.y, m.y);
      o.z = fmaf(softplus_f(r.z), e.z, m.z);
      o.w = fmaf(softplus_f(r.w), e.w, m.w);
      reinterpret_cast<float4*>(bias)[j] = o;
    }
  }
}

// ---------------- GEMM: 256x256, 4 waves (1/SIMD), per-wave 128x128 ----------------
// r10 mechanism change: 8-wave lockstep (2/SIMD) measured 6x at tile ~ LDS+MFMA
// serialized (both waves/SIMD stall on the same read-drain). Now 1 wave/SIMD:
// the wave issues its MFMA cluster non-blocking and its next quadrant's
// ds_reads drain WHILE the matrix unit grinds — self-overlap, no cross-wave
// dependency. Side benefit: 4 waves x (16KB A + 16KB B) = 128KB reads/tile
// (vs 192KB at 8 waves) -> LDS (~2050 cyc) < MFMA (2483 cyc): MFMA-bound.
// LDS 160 KiB: A ring 3 x 32 KiB + B ring 2 x 32 KiB. 1 barrier/tile.
// vmcnt ledger (4 loads per stage-call): invariant 8 outstanding entering
// tile t (= stA(t+1)); +8 stB(t+1) early, +8 stA(t+2) mid; VMCNT(8) at
// boundary drains stA(t+1)+stB(t+1) => tile t+1 published at barrier(t).
// Slot safety (max skew < 1 tile): stB(t+1) slot (t+1)&1 readers = rdB(t-1),
// drained before mfma q0(t-1) < barrier(t-1) < issue. stA(t+2) slot
// (t+2)%3=(t-1)%3 readers = rdA(t-1,*), drained by LGKM(0) pre-q3 < barrier.
// LDS swizzle: chunk ^= (row & 7) via pre-swizzled global source (linear
// global_load_lds dest) + matching XOR on ds_read (rule 21 involution).

__global__ __launch_bounds__(THREADS, 1) void gemm_bt_kernel(
    const unsigned short* __restrict__ A,   // [TOKENS][IN_F] bf16
    const unsigned short* __restrict__ B,   // [OUT_F][IN_F] bf16
    const float* __restrict__ bias,         // [OUT_F]
    float* __restrict__ C)                  // [TOKENS][OUT_F]
{
  __shared__ unsigned short lds[5 * 16384]; // 160 KiB

  const int tid  = threadIdx.x;
  const int lane = tid & 63;
  const int wave = tid >> 6;   // 0..3
  const int wm   = wave >> 1;  // 0..1
  const int wn   = wave & 1;   // 0..1

  // XCD-aware bijective block swizzle (512 = 8 XCD chunks x 64)
  const int bid = blockIdx.x;
  const int wg  = (bid & 7) * 64 + (bid >> 3);
  const int ch  = wg >> 6;
  const int idx = wg & 63;
  const int bm  = (ch >> 1) * 8 + (idx >> 3);  // 0..31
  const int bn  = (ch & 1) * 8 + (idx & 7);    // 0..15

  const int lane15 = lane & 15;
  const int cgrp   = lane >> 4;                // 0..3
  const int rdoff0 = lane15 * 64 + ((cgrp ^ (lane & 7)) * 8);
  const int rdoff1 = lane15 * 64 + (((4 + cgrp) ^ (lane & 7)) * 8);

  // staging: per-lane pre-swizzled global source (each wave stages 32 rows/half)
  const int srow = lane >> 3;                  // 0..7
  const int scol = ((lane & 7) ^ srow) * 8;    // swizzled 16B chunk -> elems
  const unsigned short* Asrc = A + (size_t)(bm * BM + wave * 32 + srow) * IN_F + scol;
  const unsigned short* Bsrc = B + (size_t)(bn * BN + wave * 32 + srow) * IN_F + scol;

  f32x4 acc[8][8] = {};   // 256 VGPR: [row-frag][col-frag], per-wave 128x128
  bf16x8 bv[8][2];        // 64 VGPR, held per tile

  auto stA = [&](int slot, int half, int t) {
    unsigned short* dst = &lds[slot * 16384 + half * 8192 + wave * 2048];
    const unsigned short* g = Asrc + (size_t)(half * 128) * IN_F + t * BK;
#pragma unroll
    for (int i = 0; i < 4; ++i)
      __builtin_amdgcn_global_load_lds((const GLOBAL_AS void*)(g + (size_t)(i * 8) * IN_F),
                                       (LDS_AS void*)(dst + i * 512), 16, 0, 0);
  };
  auto stB = [&](int slot, int half, int t) {
    unsigned short* dst = &lds[49152 + slot * 16384 + half * 8192 + wave * 2048];
    const unsigned short* g = Bsrc + (size_t)(half * 128) * IN_F + t * BK;
#pragma unroll
    for (int i = 0; i < 4; ++i)
      __builtin_amdgcn_global_load_lds((const GLOBAL_AS void*)(g + (size_t)(i * 8) * IN_F),
                                       (LDS_AS void*)(dst + i * 512), 16, 0, 0);
  };

  auto rdA = [&](const unsigned short* Ar, int q, bf16x8 (&av)[2][2]) {
#pragma unroll
    for (int f = 0; f < 2; ++f) {
      const unsigned short* p = Ar + (wm * 128 + q * 32 + f * 16) * 64;
      av[f][0] = *reinterpret_cast<const bf16x8*>(p + rdoff0);
      av[f][1] = *reinterpret_cast<const bf16x8*>(p + rdoff1);
    }
  };
  auto rdB = [&](const unsigned short* Br) {
#pragma unroll
    for (int n = 0; n < 8; ++n) {
      const unsigned short* p = Br + (wn * 128 + n * 16) * 64;
      bv[n][0] = *reinterpret_cast<const bf16x8*>(p + rdoff0);
      bv[n][1] = *reinterpret_cast<const bf16x8*>(p + rdoff1);
    }
  };
  auto mfma32 = [&](bf16x8 (&av)[2][2], int qr) {
    __builtin_amdgcn_s_setprio(1);
#pragma unroll
    for (int kk = 0; kk < 2; ++kk) {
#pragma unroll
      for (int n = 0; n < 8; ++n) {
        acc[qr * 2 + 0][n] = __builtin_amdgcn_mfma_f32_16x16x32_bf16(av[0][kk], bv[n][kk], acc[qr * 2 + 0][n], 0, 0, 0);
        acc[qr * 2 + 1][n] = __builtin_amdgcn_mfma_f32_16x16x32_bf16(av[1][kk], bv[n][kk], acc[qr * 2 + 1][n], 0, 0, 0);
      }
    }
    __builtin_amdgcn_s_setprio(0);
  };

  // prologue: stage t0 fully (16) + t1.A (8); wait t0; stB(t1) issues in tile 0
  stA(0, 0, 0); stA(0, 1, 0); stB(0, 0, 0); stB(0, 1, 0);
  stA(1, 0, 1); stA(1, 1, 1);
  VMCNT(8);
  BARRIER();

  int aslot = 0, bslot = 0;
  for (int t = 0; t < NT; ++t) {
    const unsigned short* As = &lds[aslot * 16384];
    const unsigned short* Bs = &lds[49152 + bslot * 16384];
    int a2 = aslot + 2; if (a2 >= 3) a2 -= 3;   // A slot of tile t+2
    const bool pf2 = (t + 2 < NT);
    bf16x8 avP[2][2], avX[2][2], avY[2][2];

    // quadrant-pipelined body: reads one quadrant ahead of their MFMA
    rdA(As, 0, avP);                                    // 4 ds
    rdB(Bs);                                            // +16 = 20 ds
    if (t + 1 < NT) { stB(bslot ^ 1, 0, t + 1); stB(bslot ^ 1, 1, t + 1); }  // vm+8
    rdA(As, 1, avX);                                    // 24 ds
    LGKM(4);                                            // q0 + B ready; q1 in flight
    mfma32(avP, 0);
    if (pf2) stA(a2, 0, t + 2);                         // vm+4
    rdA(As, 2, avY);                                    // 8 ds outstanding
    LGKM(4);                                            // q1 ready
    mfma32(avX, 1);
    if (pf2) stA(a2, 1, t + 2);                         // vm+4
    rdA(As, 3, avX);                                    // 8 ds
    LGKM(4);                                            // q2 ready
    mfma32(avY, 2);
    LGKM(0);                                            // q3 ready
    mfma32(avX, 3);

    // boundary: publish tile t+1 (counted; never drain in steady state)
    if (pf2)             { VMCNT(8); }
    else if (t + 1 < NT) { VMCNT(0); }
    if (t + 1 < NT) BARRIER();

    aslot = (aslot == 2) ? 0 : aslot + 1;
    bslot ^= 1;
  }

  // epilogue: C/D layout col=lane&15, row=(lane>>4)*4+reg
  const int colg0 = bn * BN + wn * 128 + lane15;
  const int rowg0 = bm * BM + wm * 128 + (lane >> 4) * 4;
#pragma unroll
  for (int ni = 0; ni < 8; ++ni) {
    const int colg = colg0 + ni * 16;
    const float bvs = bias[colg];
#pragma unroll
    for (int mi = 0; mi < 8; ++mi) {
      const int rowg = rowg0 + mi * 16;
#pragma unroll
      for (int r = 0; r < 4; ++r)
        C[(size_t)(rowg + r) * OUT_F + colg] = acc[mi][ni][r] + bvs;
    }
  }
}

// ---------------- fallback (only if ws too small) ----------------

__global__ void fallback_kernel(const float* __restrict__ x,
                                const float* __restrict__ wmu,
                                const float* __restrict__ wrho,
                                const float* __restrict__ weps,
                                const float* __restrict__ bmu,
                                const float* __restrict__ brho,
                                const float* __restrict__ beps,
                                float* __restrict__ out) {
  int o = blockIdx.x * blockDim.x + threadIdx.x;
  int t = blockIdx.y;
  float s = 0.f;
  const float* xr = x + (size_t)t * IN_F;
  const float* wm = wmu + (size_t)o * IN_F;
  const float* wr = wrho + (size_t)o * IN_F;
  const float* we = weps + (size_t)o * IN_F;
  for (int k = 0; k < IN_F; ++k)
    s += xr[k] * fmaf(softplus_f(wr[k]), we[k], wm[k]);
  out[(size_t)t * OUT_F + o] = s + fmaf(softplus_f(brho[o]), beps[o], bmu[o]);
}

// ---------------- launch ----------------

extern "C" void kernel_launch(void* const* d_in, const int* in_sizes, int n_in,
                              void* d_out, int out_size, void* d_ws, size_t ws_size,
                              hipStream_t stream) {
  const float* x    = (const float*)d_in[0];
  const float* wmu  = (const float*)d_in[1];
  const float* wrho = (const float*)d_in[2];
  const float* bmu  = (const float*)d_in[3];
  const float* brho = (const float*)d_in[4];
  const float* weps = (const float*)d_in[5];
  const float* beps = (const float*)d_in[6];
  float* out = (float*)d_out;

  const size_t xb_off   = 0;
  const size_t wb_off   = (size_t)TOKENS * IN_F * 2;            // 64 MB
  const size_t bias_off = wb_off + (size_t)OUT_F * IN_F * 2;    // +32 MB
  const size_t needed   = bias_off + (size_t)OUT_F * 4;

  if (ws_size < needed) {
    dim3 g(OUT_F / 256, TOKENS);
    hipLaunchKernelGGL(fallback_kernel, g, dim3(256), 0, stream,
                       x, wmu, wrho, weps, bmu, brho, beps, out);
    return;
  }

  unsigned short* xb = (unsigned short*)((char*)d_ws + xb_off);
  unsigned short* wb = (unsigned short*)((char*)d_ws + wb_off);
  float* bias = (float*)((char*)d_ws + bias_off);

  hipLaunchKernelGGL(prep_kernel, dim3(2048), dim3(256), 0, stream,
                     x, wmu, wrho, weps, bmu, brho, beps, xb, wb, bias);

  hipLaunchKernelGGL(gemm_bt_kernel,
                     dim3((TOKENS / BM) * (OUT_F / BN)), dim3(THREADS), 0, stream,
                     xb, wb, bias, out);
}

// Round 11
// 310.729 us; speedup vs baseline: 1.0134x; 1.0056x over previous
//
#include <hip/hip_runtime.h>
#include <hip/hip_bf16.h>
#include <cstdint>

#define TOKENS 8192
#define IN_F   4096
#define OUT_F  4096

#define BM 256
#define BN 256
#define BK 64
#define NT (IN_F / BK)   // 64 K-tiles
#define THREADS 512

typedef __attribute__((ext_vector_type(8))) short bf16x8;
typedef __attribute__((ext_vector_type(4))) float f32x4;

#define GLOBAL_AS __attribute__((address_space(1)))
#define LDS_AS    __attribute__((address_space(3)))

#define BARRIER() __builtin_amdgcn_s_barrier()
// boundary vmcnt: SB0 on BOTH sides so no VMEM op is emitted across the
// ledger point (plain asm is not a scheduling fence for independent loads)
#define VMCNTB(n) do { __builtin_amdgcn_sched_barrier(0); \
                       asm volatile("s_waitcnt vmcnt(" #n ")"); \
                       __builtin_amdgcn_sched_barrier(0); } while (0)
// sched_group_barrier masks: MFMA=0x8, DS_READ=0x100
#define SGB(mask, n) __builtin_amdgcn_sched_group_barrier(mask, n, 0)

__device__ __forceinline__ unsigned short f2bf(float f) {
  union { float f; unsigned int u; } v;
  v.f = f;
  unsigned int r = 0x7FFFu + ((v.u >> 16) & 1u);
  return (unsigned short)((v.u + r) >> 16);
}

__device__ __forceinline__ float softplus_f(float x) {
  return log1pf(expf(x));
}

// ---------------- fused prep kernel ----------------

#define NW4 ((long long)OUT_F * IN_F / 4)
#define NX4 ((long long)TOKENS * IN_F / 4)
#define NB4 (OUT_F / 4)

__global__ void prep_kernel(const float* __restrict__ x,
                            const float* __restrict__ wmu,
                            const float* __restrict__ wrho,
                            const float* __restrict__ weps,
                            const float* __restrict__ bmu,
                            const float* __restrict__ brho,
                            const float* __restrict__ beps,
                            unsigned short* __restrict__ xb,
                            unsigned short* __restrict__ wb,
                            float* __restrict__ bias) {
  long long i = (long long)blockIdx.x * blockDim.x + threadIdx.x;
  long long stride = (long long)gridDim.x * blockDim.x;
  const long long total = NW4 + NX4 + NB4;
  for (; i < total; i += stride) {
    if (i < NW4) {
      float4 m = reinterpret_cast<const float4*>(wmu)[i];
      float4 r = reinterpret_cast<const float4*>(wrho)[i];
      float4 e = reinterpret_cast<const float4*>(weps)[i];
      ushort4 o;
      o.x = f2bf(fmaf(softplus_f(r.x), e.x, m.x));
      o.y = f2bf(fmaf(softplus_f(r.y), e.y, m.y));
      o.z = f2bf(fmaf(softplus_f(r.z), e.z, m.z));
      o.w = f2bf(fmaf(softplus_f(r.w), e.w, m.w));
      reinterpret_cast<ushort4*>(wb)[i] = o;
    } else if (i < NW4 + NX4) {
      long long j = i - NW4;
      float4 m = reinterpret_cast<const float4*>(x)[j];
      ushort4 o;
      o.x = f2bf(m.x); o.y = f2bf(m.y); o.z = f2bf(m.z); o.w = f2bf(m.w);
      reinterpret_cast<ushort4*>(xb)[j] = o;
    } else {
      long long j = i - NW4 - NX4;
      float4 m = reinterpret_cast<const float4*>(bmu)[j];
      float4 r = reinterpret_cast<const float4*>(brho)[j];
      float4 e = reinterpret_cast<const float4*>(beps)[j];
      float4 o;
      o.x = fmaf(softplus_f(r.x), e.x, m.x);
      o.y = fmaf(softplus_f(r.y), e.y, m.y);
      o.z = fmaf(softplus_f(r.z), e.z, m.z);
      o.w = fmaf(softplus_f(r.w), e.w, m.w);
      reinterpret_cast<float4*>(bias)[j] = o;
    }
  }
}

// ---------------- GEMM: 256x256, r9 free-flow + T19 emission interleave ----------------
// r11 change (single variable vs r9): intra-tile LGKM walls removed (the
// compiler's automatic counted lgkmcnt is already optimal); emission order is
// pinned with sched_group_barrier so ds_reads are threaded BETWEEN MFMAs:
//   region A: R12 (B+q0) then {M3,R1}x4 (q1 reads inside q0 cluster), M4
//   region B: {M2,R1}x4 (q2 reads), M8, {R1,M4}x4 (q3 reads, WAR-safe after
//             q1's 16 MFMAs), M16
// This is AITER's 1:1 MFMA<->ds_read interleave (m196's "lever"), attacking
// the measured additive-pipes signature (7 schedules all at tile =
// LDS-time + MFMA-time). Hazards (unchanged from r9, now auto-waitcnt based):
//   - stB into current B slot after bar1: each wave's B ds_reads retire
//     before its q0 MFMAs issue (reg dependency) => drained at bar1.
//   - A-ring slot (t+2)%3: readers were tile t-1's q3 MFMAs, drained before
//     tile-(t-1) end barrier.
//   - staging publish: VMCNTB(6)+barrier once per tile (counted, never 0 in
//     steady state); SB0 both sides keeps the vmem ledger exact.
// LDS swizzle: chunk ^= (row & 7) via pre-swizzled global source (linear
// global_load_lds dest) + matching XOR on ds_read (rule 21 involution).

__global__ __launch_bounds__(THREADS, 2) void gemm_bt_kernel(
    const unsigned short* __restrict__ A,   // [TOKENS][IN_F] bf16
    const unsigned short* __restrict__ B,   // [OUT_F][IN_F] bf16
    const float* __restrict__ bias,         // [OUT_F]
    float* __restrict__ C)                  // [TOKENS][OUT_F]
{
  __shared__ unsigned short lds[5 * 16384]; // 160 KiB

  const int tid  = threadIdx.x;
  const int lane = tid & 63;
  const int wave = tid >> 6;   // 0..7
  const int wm   = wave >> 2;  // 0..1
  const int wn   = wave & 3;   // 0..3

  // XCD-aware bijective block swizzle (512 = 8 XCD chunks x 64)
  const int bid = blockIdx.x;
  const int wg  = (bid & 7) * 64 + (bid >> 3);
  const int ch  = wg >> 6;
  const int idx = wg & 63;
  const int bm  = (ch >> 1) * 8 + (idx >> 3);  // 0..31
  const int bn  = (ch & 1) * 8 + (idx & 7);    // 0..15

  const int lane15 = lane & 15;
  const int cgrp   = lane >> 4;                // 0..3
  const int rdoff0 = lane15 * 64 + ((cgrp ^ (lane & 7)) * 8);
  const int rdoff1 = lane15 * 64 + (((4 + cgrp) ^ (lane & 7)) * 8);

  // staging: per-lane pre-swizzled global source
  const int srow = lane >> 3;                  // 0..7
  const int scol = ((lane & 7) ^ srow) * 8;    // swizzled 16B chunk -> elems
  const unsigned short* Asrc = A + (size_t)(bm * BM + wave * 16 + srow) * IN_F + scol;
  const unsigned short* Bsrc = B + (size_t)(bn * BN + wave * 16 + srow) * IN_F + scol;

  f32x4 acc[8][4] = {};

  auto stA = [&](int slot, int half, int t) {
    unsigned short* dst = &lds[slot * 16384 + half * 8192 + wave * 1024];
    const unsigned short* g = Asrc + (size_t)(half * 128) * IN_F + t * BK;
    __builtin_amdgcn_global_load_lds((const GLOBAL_AS void*)g,
                                     (LDS_AS void*)dst, 16, 0, 0);
    __builtin_amdgcn_global_load_lds((const GLOBAL_AS void*)(g + (size_t)8 * IN_F),
                                     (LDS_AS void*)(dst + 512), 16, 0, 0);
  };
  auto stB = [&](int slot, int half, int t) {
    unsigned short* dst = &lds[49152 + slot * 16384 + half * 8192 + wave * 1024];
    const unsigned short* g = Bsrc + (size_t)(half * 128) * IN_F + t * BK;
    __builtin_amdgcn_global_load_lds((const GLOBAL_AS void*)g,
                                     (LDS_AS void*)dst, 16, 0, 0);
    __builtin_amdgcn_global_load_lds((const GLOBAL_AS void*)(g + (size_t)8 * IN_F),
                                     (LDS_AS void*)(dst + 512), 16, 0, 0);
  };

  auto rdA = [&](const unsigned short* Ar, int q, bf16x8 (&av)[2][2]) {
#pragma unroll
    for (int f = 0; f < 2; ++f) {
      const unsigned short* p = Ar + (wm * 128 + q * 32 + f * 16) * 64;
      av[f][0] = *reinterpret_cast<const bf16x8*>(p + rdoff0);
      av[f][1] = *reinterpret_cast<const bf16x8*>(p + rdoff1);
    }
  };
  auto rdB = [&](const unsigned short* Br, bf16x8 (&bv)[4][2]) {
#pragma unroll
    for (int n = 0; n < 4; ++n) {
      const unsigned short* p = Br + (wn * 64 + n * 16) * 64;
      bv[n][0] = *reinterpret_cast<const bf16x8*>(p + rdoff0);
      bv[n][1] = *reinterpret_cast<const bf16x8*>(p + rdoff1);
    }
  };
  auto mfma16 = [&](bf16x8 (&av)[2][2], bf16x8 (&bv)[4][2], f32x4* r0, f32x4* r1) {
    __builtin_amdgcn_s_setprio(1);
#pragma unroll
    for (int kk = 0; kk < 2; ++kk) {
#pragma unroll
      for (int n = 0; n < 4; ++n) {
        r0[n] = __builtin_amdgcn_mfma_f32_16x16x32_bf16(av[0][kk], bv[n][kk], r0[n], 0, 0, 0);
        r1[n] = __builtin_amdgcn_mfma_f32_16x16x32_bf16(av[1][kk], bv[n][kk], r1[n], 0, 0, 0);
      }
    }
    __builtin_amdgcn_s_setprio(0);
  };

  // prologue: stage t0 fully, then t1 fully; wait t0 (8 newest stay in flight)
  stA(0, 0, 0); stA(0, 1, 0); stB(0, 0, 0); stB(0, 1, 0);
  stA(1, 0, 1); stA(1, 1, 1); stB(1, 0, 1); stB(1, 1, 1);
  VMCNTB(8);
  BARRIER();

  int aslot = 0, bslot = 0;
  for (int t = 0; t < NT; ++t) {
    const unsigned short* As = &lds[aslot * 16384];
    const unsigned short* Bs = &lds[49152 + bslot * 16384];
    int a2 = aslot + 2; if (a2 >= 3) a2 -= 3;   // A slot of tile t+2
    const bool pf = (t + 2 < NT);
    bf16x8 avX[2][2], avY[2][2], bv[4][2];

    // ---- region A: B + q0 + q1 reads, q0 cluster, stage (t+2).A ----
    rdB(Bs, bv);
    rdA(As, 0, avX);
    if (pf) { stA(a2, 0, t + 2); stA(a2, 1, t + 2); }
    rdA(As, 1, avY);
    mfma16(avX, bv, acc[0], acc[1]);             // q0
    // emission script: R12 first, then q1 reads threaded through q0 cluster
    SGB(0x100, 12);
    SGB(0x8, 3); SGB(0x100, 1);
    SGB(0x8, 3); SGB(0x100, 1);
    SGB(0x8, 3); SGB(0x100, 1);
    SGB(0x8, 3); SGB(0x100, 1);
    SGB(0x8, 4);
    BARRIER();   // bar1: B reads drained (reg deps) => B-slot restage safe

    // ---- region B: q1..q3 clusters with q2/q3 reads interleaved ----
    if (pf) stB(bslot, 0, t + 2);
    rdA(As, 2, avX);                             // q2 (WAR vs q0: prev region)
    mfma16(avY, bv, acc[2], acc[3]);             // q1
    if (pf) stB(bslot, 1, t + 2);
    rdA(As, 3, avY);                             // q3 (WAR: after q1 MFMAs)
    mfma16(avX, bv, acc[4], acc[5]);             // q2
    mfma16(avY, bv, acc[6], acc[7]);             // q3
    // emission script: q2 reads inside q1 cluster; q3 reads after q1 (WAR)
    SGB(0x8, 2); SGB(0x100, 1);
    SGB(0x8, 2); SGB(0x100, 1);
    SGB(0x8, 2); SGB(0x100, 1);
    SGB(0x8, 2); SGB(0x100, 1);
    SGB(0x8, 8);
    SGB(0x100, 1); SGB(0x8, 4);
    SGB(0x100, 1); SGB(0x8, 4);
    SGB(0x100, 1); SGB(0x8, 4);
    SGB(0x100, 1); SGB(0x8, 4);
    SGB(0x8, 16);

    // boundary: publish tile t+1 (counted; never drain in steady state)
    if (pf)              { VMCNTB(6); }
    else if (t + 1 < NT) { VMCNTB(0); }
    if (t + 1 < NT) BARRIER();                   // bar2

    aslot = (aslot == 2) ? 0 : aslot + 1;
    bslot ^= 1;
  }

  // epilogue: C/D layout col=lane&15, row=(lane>>4)*4+reg
  const int colg0 = bn * BN + wn * 64 + lane15;
  const int rowg0 = bm * BM + wm * 128 + (lane >> 4) * 4;
#pragma unroll
  for (int ni = 0; ni < 4; ++ni) {
    const int colg = colg0 + ni * 16;
    const float bvs = bias[colg];
#pragma unroll
    for (int mi = 0; mi < 8; ++mi) {
      const int rowg = rowg0 + mi * 16;
#pragma unroll
      for (int r = 0; r < 4; ++r)
        C[(size_t)(rowg + r) * OUT_F + colg] = acc[mi][ni][r] + bvs;
    }
  }
}

// ---------------- fallback (only if ws too small) ----------------

__global__ void fallback_kernel(const float* __restrict__ x,
                                const float* __restrict__ wmu,
                                const float* __restrict__ wrho,
                                const float* __restrict__ weps,
                                const float* __restrict__ bmu,
                                const float* __restrict__ brho,
                                const float* __restrict__ beps,
                                float* __restrict__ out) {
  int o = blockIdx.x * blockDim.x + threadIdx.x;
  int t = blockIdx.y;
  float s = 0.f;
  const float* xr = x + (size_t)t * IN_F;
  const float* wm = wmu + (size_t)o * IN_F;
  const float* wr = wrho + (size_t)o * IN_F;
  const float* we = weps + (size_t)o * IN_F;
  for (int k = 0; k < IN_F; ++k)
    s += xr[k] * fmaf(softplus_f(wr[k]), we[k], wm[k]);
  out[(size_t)t * OUT_F + o] = s + fmaf(softplus_f(brho[o]), beps[o], bmu[o]);
}

// ---------------- launch ----------------

extern "C" void kernel_launch(void* const* d_in, const int* in_sizes, int n_in,
                              void* d_out, int out_size, void* d_ws, size_t ws_size,
                              hipStream_t stream) {
  const float* x    = (const float*)d_in[0];
  const float* wmu  = (const float*)d_in[1];
  const float* wrho = (const float*)d_in[2];
  const float* bmu  = (const float*)d_in[3];
  const float* brho = (const float*)d_in[4];
  const float* weps = (const float*)d_in[5];
  const float* beps = (const float*)d_in[6];
  float* out = (float*)d_out;

  const size_t xb_off   = 0;
  const size_t wb_off   = (size_t)TOKENS * IN_F * 2;            // 64 MB
  const size_t bias_off = wb_off + (size_t)OUT_F * IN_F * 2;    // +32 MB
  const size_t needed   = bias_off + (size_t)OUT_F * 4;

  if (ws_size < needed) {
    dim3 g(OUT_F / 256, TOKENS);
    hipLaunchKernelGGL(fallback_kernel, g, dim3(256), 0, stream,
                       x, wmu, wrho, weps, bmu, brho, beps, out);
    return;
  }

  unsigned short* xb = (unsigned short*)((char*)d_ws + xb_off);
  unsigned short* wb = (unsigned short*)((char*)d_ws + wb_off);
  float* bias = (float*)((char*)d_ws + bias_off);

  hipLaunchKernelGGL(prep_kernel, dim3(2048), dim3(256), 0, stream,
                     x, wmu, wrho, weps, bmu, brho, beps, xb, wb, bias);

  hipLaunchKernelGGL(gemm_bt_kernel,
                     dim3((TOKENS / BM) * (OUT_F / BN)), dim3(THREADS), 0, stream,
                     xb, wb, bias, out);
}